// Round 6
// baseline (1153.681 us; speedup 1.0000x reference)
//
#include <hip/hip_runtime.h>
#include <stdint.h>
#include <math.h>

#define IN_DIM 512
#define HID    256
#define OUTD   128
#define LN_EPS 1e-5f

typedef unsigned short u16;
typedef unsigned int   u32;
typedef short short8 __attribute__((ext_vector_type(8)));
typedef float f32x4  __attribute__((ext_vector_type(4)));

__device__ __forceinline__ float bf2f(u32 h) {
  union { u32 u; float f; } c; c.u = h << 16; return c.f;
}
__device__ __forceinline__ u16 f2bf(float f) {
  union { float f; u32 u; } c; c.f = f;
  u32 u = c.u;
  return (u16)((u + 0x7FFFu + ((u >> 16) & 1u)) >> 16);  // RNE
}

__device__ __forceinline__ void gload_lds16(const void* g, void* l) {
  __builtin_amdgcn_global_load_lds((const __attribute__((address_space(1))) void*)g,
                                   (__attribute__((address_space(3))) void*)l, 16, 0, 0);
}

// ================= K1: mega-prep (block-region dispatch) =====================
// regions: [0,b_cvt) x->bf16 | [.,+b_hist) histogram | [.,+6) bias concat |
//          [.,+512) W1 transpose tiles | [.,+128) W2 transpose tiles
__global__ __launch_bounds__(256) void k_prep(
    const float* __restrict__ x, u16* __restrict__ x_bf, int n4,
    const int* __restrict__ edst, int* __restrict__ deg, int E,
    const float* __restrict__ bq1, const float* __restrict__ bk1,
    const float* __restrict__ bv1, const float* __restrict__ bs1,
    const float* __restrict__ bq2, const float* __restrict__ bk2,
    const float* __restrict__ bv2, const float* __restrict__ bs2,
    float* __restrict__ bc1, float* __restrict__ bc2,
    const float* __restrict__ Wq1, const float* __restrict__ Wk1,
    const float* __restrict__ Wv1, const float* __restrict__ Ws1,
    const float* __restrict__ Wq2, const float* __restrict__ Wk2,
    const float* __restrict__ Wv2, const float* __restrict__ Ws2,
    u16* __restrict__ Wt1, u16* __restrict__ Wt2,
    int b_cvt, int b_hist) {
  __shared__ u16 t[32][33];
  int blk = blockIdx.x;
  int tid = threadIdx.x;
  if (blk < b_cvt) {
    int id = blk * 256 + tid;
    if (id < n4) {
      const float4 v = ((const float4*)x)[id];
      ushort4 o;
      o.x = f2bf(v.x); o.y = f2bf(v.y); o.z = f2bf(v.z); o.w = f2bf(v.w);
      ((ushort4*)x_bf)[id] = o;
    }
    return;
  }
  blk -= b_cvt;
  if (blk < b_hist) {
    int e = blk * 256 + tid;
    if (e < E) atomicAdd(&deg[edst[e]], 1);
    return;
  }
  blk -= b_hist;
  if (blk < 6) {
    int id = blk * 256 + tid;
    if (id < 4 * HID) {
      const float* s = (id < HID) ? bq1 : (id < 2 * HID) ? bk1 : (id < 3 * HID) ? bv1 : bs1;
      bc1[id] = s[id & (HID - 1)];
    } else if (id < 4 * HID + 4 * OUTD) {
      int j = id - 4 * HID;
      const float* s = (j < OUTD) ? bq2 : (j < 2 * OUTD) ? bk2 : (j < 3 * OUTD) ? bv2 : bs2;
      bc2[j] = s[j & (OUTD - 1)];
    }
    return;
  }
  blk -= 6;
  int tx = tid & 31, ty = tid >> 5;
  if (blk < 512) {  // W1: K=512, Nw=256; per-mat 16x8 tiles
    int mat = blk >> 7, r = blk & 127;
    int k0 = (r >> 3) * 32, n0 = (r & 7) * 32;
    const float* src = (mat == 0) ? Wq1 : (mat == 1) ? Wk1 : (mat == 2) ? Wv1 : Ws1;
    u16* dst = Wt1 + (size_t)mat * IN_DIM * HID;
#pragma unroll
    for (int i = 0; i < 32; i += 8)
      t[ty + i][tx] = f2bf(src[(size_t)(k0 + ty + i) * HID + n0 + tx]);
    __syncthreads();
#pragma unroll
    for (int i = 0; i < 32; i += 8)
      dst[(size_t)(n0 + ty + i) * IN_DIM + k0 + tx] = t[tx][ty + i];
    return;
  }
  blk -= 512;
  {  // W2: K=256, Nw=128; per-mat 8x4 tiles
    int mat = blk >> 5, r = blk & 31;
    int k0 = (r >> 2) * 32, n0 = (r & 3) * 32;
    const float* src = (mat == 0) ? Wq2 : (mat == 1) ? Wk2 : (mat == 2) ? Wv2 : Ws2;
    u16* dst = Wt2 + (size_t)mat * HID * OUTD;
#pragma unroll
    for (int i = 0; i < 32; i += 8)
      t[ty + i][tx] = f2bf(src[(size_t)(k0 + ty + i) * OUTD + n0 + tx]);
    __syncthreads();
#pragma unroll
    for (int i = 0; i < 32; i += 8)
      dst[(size_t)(n0 + ty + i) * HID + k0 + tx] = t[tx][ty + i];
  }
}

// ================= K2: single-workgroup exclusive scan =======================
__global__ __launch_bounds__(1024) void k_scan(const int* __restrict__ deg,
                                               int* __restrict__ offsets,
                                               int* __restrict__ cur, int n, int total) {
  __shared__ int sm[1024];
  int t = threadIdx.x;
  int chunk = (n + 1023) / 1024;
  int base = t * chunk;
  int s = 0;
  for (int i = base; i < base + chunk && i < n; ++i) s += deg[i];
  sm[t] = s;
  __syncthreads();
  for (int off = 1; off < 1024; off <<= 1) {
    int v = (t >= off) ? sm[t - off] : 0;
    __syncthreads();
    sm[t] += v;
    __syncthreads();
  }
  int run = sm[t] - s;  // exclusive
  for (int i = base; i < base + chunk && i < n; ++i) {
    offsets[i] = run;
    cur[i] = run;
    run += deg[i];
  }
  if (t == 0) offsets[n] = total;
}

// ================= K3/K6: bf16 NT GEMM (m97) + optional scatter region =======
// XCD swizzle: bid = ((grp*nbn + n)<<3)|xcd, m = grp*8+xcd -> the nbn blocks
// sharing an A row-block have ids differing by 8 (same XCD under round-robin)
// and dispatch within 8*nbn of each other -> A staged once per XCD L2.
__global__ __launch_bounds__(256) void k_gemm_sc(
    const u16* __restrict__ A, const u16* __restrict__ Bt, const float* __restrict__ bias,
    u16* __restrict__ C, int M, int K, int Nt, int nbn, int gemm_blocks,
    const int* __restrict__ esrc, const int* __restrict__ edst,
    int* __restrict__ cur, int* __restrict__ ssrc, int E) {
  if ((int)blockIdx.x >= gemm_blocks) {  // scatter region
    int e = (blockIdx.x - gemm_blocks) * 256 + threadIdx.x;
    if (e < E) {
      int d = edst[e];
      int pos = atomicAdd(&cur[d], 1);
      ssrc[pos] = esrc[e];
    }
    return;
  }
  int bid = blockIdx.x;
  int xcd = bid & 7;
  int nm = bid >> 3;
  int n = nm % nbn;
  int m = (nm / nbn) * 8 + xcd;
  if (m * 128 >= M) return;

  __shared__ __align__(16) u16 As[128 * 32];
  __shared__ __align__(16) u16 Bs[128 * 32];
  const int tid = threadIdx.x;
  const int bm0 = m * 128;
  const int bn0 = n * 128;
  const int wave = tid >> 6, lane = tid & 63;
  const int q = lane >> 4, r16 = lane & 15;
  const int wm = (wave >> 1) * 64, wn = (wave & 1) * 64;

  f32x4 acc[4][4];
#pragma unroll
  for (int i = 0; i < 4; i++)
#pragma unroll
    for (int j = 0; j < 4; j++) acc[i][j] = (f32x4){0.f, 0.f, 0.f, 0.f};

  const int r0 = tid >> 2;
  const int c0 = (tid & 3) * 8;

  for (int kt = 0; kt < K; kt += 32) {
#pragma unroll
    for (int h = 0; h < 2; ++h) {
      int row = r0 + h * 64;
      gload_lds16(A + (size_t)(bm0 + row) * K + kt + c0, &As[row * 32 + c0]);
      gload_lds16(Bt + (size_t)(bn0 + row) * K + kt + c0, &Bs[row * 32 + c0]);
    }
    __syncthreads();
    short8 af[4], bfr[4];
#pragma unroll
    for (int i = 0; i < 4; i++) af[i] = *(const short8*)(&As[(wm + i * 16 + r16) * 32 + q * 8]);
#pragma unroll
    for (int j = 0; j < 4; j++) bfr[j] = *(const short8*)(&Bs[(wn + j * 16 + r16) * 32 + q * 8]);
#pragma unroll
    for (int i = 0; i < 4; i++)
#pragma unroll
      for (int j = 0; j < 4; j++)
        acc[i][j] = __builtin_amdgcn_mfma_f32_16x16x32_bf16(af[i], bfr[j], acc[i][j], 0, 0, 0);
    __syncthreads();
  }

#pragma unroll
  for (int i = 0; i < 4; i++) {
#pragma unroll
    for (int r = 0; r < 4; r++) {
      int grow = bm0 + wm + i * 16 + q * 4 + r;
      if (grow >= M) continue;
      size_t rbase = (size_t)grow * Nt;
#pragma unroll
      for (int j = 0; j < 4; j++) {
        int gcol = bn0 + wn + j * 16 + r16;
        float v = acc[i][j][r] + bias[gcol];
        C[rbase + gcol] = f2bf(v);
      }
    }
  }
}

// ================= K4/K7: conv (R2 structure) + fused global stats ===========
template <int VPL>
__device__ __forceinline__ void load_bf(const u16* __restrict__ p, int lane, float* f) {
  if constexpr (VPL == 4) {
    uint2 r = *(const uint2*)(p + lane * 4);
    f[0] = bf2f(r.x & 0xffffu); f[1] = bf2f(r.x >> 16);
    f[2] = bf2f(r.y & 0xffffu); f[3] = bf2f(r.y >> 16);
  } else {
    u32 r = *(const u32*)(p + lane * 2);
    f[0] = bf2f(r & 0xffffu); f[1] = bf2f(r >> 16);
  }
}

template <int H, bool OUT_BF16>
__global__ __launch_bounds__(256) void k_conv(
    const u16* __restrict__ qkvs, const int* __restrict__ offsets,
    const int* __restrict__ ssrc, u16* __restrict__ out_bf,
    float* __restrict__ out_f, int n, float scale, double* __restrict__ st) {
  constexpr int VPL = H / 64;
  int gw = (blockIdx.x * blockDim.x + threadIdx.x) >> 6;
  int wave = threadIdx.x >> 6;
  int lane = threadIdx.x & 63;
  bool live = gw < n;
  float r[VPL];
#pragma unroll
  for (int w = 0; w < VPL; w++) r[w] = 0.f;

  if (live) {
    const u16* base = qkvs + (size_t)gw * (4 * H);
    float qf[VPL];
    load_bf<VPL>(base, lane, qf);
    int beg = offsets[gw], end = offsets[gw + 1];
    float m = -INFINITY, l = 0.f;
    float agg[VPL];
#pragma unroll
    for (int w = 0; w < VPL; w++) agg[w] = 0.f;

    int i = beg;
    for (; i + 4 <= end; i += 4) {
      int s0 = ssrc[i], s1 = ssrc[i + 1], s2 = ssrc[i + 2], s3 = ssrc[i + 3];
      const u16* k0p = qkvs + (size_t)s0 * (4 * H) + H;
      const u16* k1p = qkvs + (size_t)s1 * (4 * H) + H;
      const u16* k2p = qkvs + (size_t)s2 * (4 * H) + H;
      const u16* k3p = qkvs + (size_t)s3 * (4 * H) + H;
      float k0[VPL], k1[VPL], k2[VPL], k3[VPL];
      float v0[VPL], v1[VPL], v2[VPL], v3[VPL];
      load_bf<VPL>(k0p, lane, k0);
      load_bf<VPL>(k1p, lane, k1);
      load_bf<VPL>(k2p, lane, k2);
      load_bf<VPL>(k3p, lane, k3);
      load_bf<VPL>(k0p + H, lane, v0);
      load_bf<VPL>(k1p + H, lane, v1);
      load_bf<VPL>(k2p + H, lane, v2);
      load_bf<VPL>(k3p + H, lane, v3);
      float d0 = 0.f, d1 = 0.f, d2 = 0.f, d3 = 0.f;
#pragma unroll
      for (int w = 0; w < VPL; w++) {
        d0 += qf[w] * k0[w]; d1 += qf[w] * k1[w];
        d2 += qf[w] * k2[w]; d3 += qf[w] * k3[w];
      }
#pragma unroll
      for (int off = 32; off > 0; off >>= 1) {
        d0 += __shfl_xor(d0, off, 64);
        d1 += __shfl_xor(d1, off, 64);
        d2 += __shfl_xor(d2, off, 64);
        d3 += __shfl_xor(d3, off, 64);
      }
      d0 *= scale; d1 *= scale; d2 *= scale; d3 *= scale;
      float cm = fmaxf(fmaxf(d0, d1), fmaxf(d2, d3));
      float nm = fmaxf(m, cm);
      float sc = __expf(m - nm);  // m=-inf first round -> 0
      float p0 = __expf(d0 - nm), p1 = __expf(d1 - nm);
      float p2 = __expf(d2 - nm), p3 = __expf(d3 - nm);
      m = nm;
      l = l * sc + (p0 + p1) + (p2 + p3);
#pragma unroll
      for (int w = 0; w < VPL; w++)
        agg[w] = agg[w] * sc + p0 * v0[w] + p1 * v1[w] + p2 * v2[w] + p3 * v3[w];
    }
    for (; i < end; ++i) {
      int s = ssrc[i];
      const u16* kb = qkvs + (size_t)s * (4 * H) + H;
      float kf[VPL], vf[VPL];
      load_bf<VPL>(kb, lane, kf);
      load_bf<VPL>(kb + H, lane, vf);
      float d = 0.f;
#pragma unroll
      for (int w = 0; w < VPL; w++) d += qf[w] * kf[w];
#pragma unroll
      for (int off = 32; off > 0; off >>= 1) d += __shfl_xor(d, off, 64);
      float score = d * scale;
      float nm = fmaxf(m, score);
      float sc = __expf(m - nm);
      float p = __expf(score - nm);
      m = nm;
      l = l * sc + p;
#pragma unroll
      for (int w = 0; w < VPL; w++) agg[w] = agg[w] * sc + p * vf[w];
    }

    float sf[VPL];
    load_bf<VPL>(base + 3 * H, lane, sf);
    float inv = (end > beg) ? 1.f / l : 0.f;
#pragma unroll
    for (int w = 0; w < VPL; w++) r[w] = agg[w] * inv + sf[w];
    if (OUT_BF16) {
#pragma unroll
      for (int w = 0; w < VPL; w++) out_bf[(size_t)gw * H + lane * VPL + w] = f2bf(r[w]);
    } else {
#pragma unroll
      for (int w = 0; w < VPL; w++) out_f[(size_t)gw * H + lane * VPL + w] = r[w];
    }
  }

  // fused global stats (wave shfl-reduce -> LDS -> 2 atomics per block)
  float s = 0.f, s2 = 0.f;
#pragma unroll
  for (int w = 0; w < VPL; w++) { s += r[w]; s2 += r[w] * r[w]; }
#pragma unroll
  for (int off = 32; off > 0; off >>= 1) {
    s += __shfl_xor(s, off, 64);
    s2 += __shfl_xor(s2, off, 64);
  }
  __shared__ float bsm[8];
  if (lane == 0) { bsm[wave * 2] = s; bsm[wave * 2 + 1] = s2; }
  __syncthreads();
  if (threadIdx.x == 0) {
    atomicAdd(&st[0], (double)(bsm[0] + bsm[2] + bsm[4] + bsm[6]));
    atomicAdd(&st[1], (double)(bsm[1] + bsm[3] + bsm[5] + bsm[7]));
  }
}

// ================= K5/K8: layernorm apply (stats finalized inline) ===========
__global__ void k_norm_elu_bf16(const u16* __restrict__ a, const float* __restrict__ g,
                                const float* __restrict__ b, const double* __restrict__ st,
                                double cnt, u16* __restrict__ out, int n8, int Hmask) {
  int id = blockIdx.x * blockDim.x + threadIdx.x;
  if (id >= n8) return;
  double mud = st[0] / cnt;
  double var = st[1] / cnt - mud * mud;
  if (var < 0.0) var = 0.0;
  float mu = (float)mud;
  float inv = (float)(1.0 / (sqrt(var) + (double)LN_EPS));
  int i8 = id * 8;
  int cb = i8 & Hmask;
  uint4 v = *(const uint4*)(a + i8);
  const u32 va[4] = {v.x, v.y, v.z, v.w};
  uint4 o;
  u32* op = (u32*)&o;
#pragma unroll
  for (int w = 0; w < 4; w++) {
    float y0 = (bf2f(va[w] & 0xffffu) - mu) * inv * g[cb + 2 * w] + b[cb + 2 * w];
    float y1 = (bf2f(va[w] >> 16) - mu) * inv * g[cb + 2 * w + 1] + b[cb + 2 * w + 1];
    y0 = (y0 > 0.f) ? y0 : (__expf(y0) - 1.f);
    y1 = (y1 > 0.f) ? y1 : (__expf(y1) - 1.f);
    op[w] = (u32)f2bf(y0) | ((u32)f2bf(y1) << 16);
  }
  *(uint4*)(out + i8) = o;
}

__global__ void k_norm_f32(float* __restrict__ a, const float* __restrict__ g,
                           const float* __restrict__ b, const double* __restrict__ st,
                           double cnt, int n4, int Hmask) {
  int id = blockIdx.x * blockDim.x + threadIdx.x;
  if (id >= n4) return;
  double mud = st[0] / cnt;
  double var = st[1] / cnt - mud * mud;
  if (var < 0.0) var = 0.0;
  float mu = (float)mud;
  float inv = (float)(1.0 / (sqrt(var) + (double)LN_EPS));
  int i4 = id * 4;
  int cb = i4 & Hmask;
  float4 v = *(const float4*)(a + i4);
  float4 o;
  o.x = (v.x - mu) * inv * g[cb] + b[cb];
  o.y = (v.y - mu) * inv * g[cb + 1] + b[cb + 1];
  o.z = (v.z - mu) * inv * g[cb + 2] + b[cb + 2];
  o.w = (v.w - mu) * inv * g[cb + 3] + b[cb + 3];
  *(float4*)(a + i4) = o;
}

// ================= launch ====================================================
extern "C" void kernel_launch(void* const* d_in, const int* in_sizes, int n_in,
                              void* d_out, int out_size, void* d_ws, size_t ws_size,
                              hipStream_t stream) {
  const float* x   = (const float*)d_in[0];
  const float* Wq1 = (const float*)d_in[1];  const float* bq1 = (const float*)d_in[2];
  const float* Wk1 = (const float*)d_in[3];  const float* bk1 = (const float*)d_in[4];
  const float* Wv1 = (const float*)d_in[5];  const float* bv1 = (const float*)d_in[6];
  const float* Ws1 = (const float*)d_in[7];  const float* bs1 = (const float*)d_in[8];
  const float* g1  = (const float*)d_in[9];  const float* be1 = (const float*)d_in[10];
  const float* Wq2 = (const float*)d_in[11]; const float* bq2 = (const float*)d_in[12];
  const float* Wk2 = (const float*)d_in[13]; const float* bk2 = (const float*)d_in[14];
  const float* Wv2 = (const float*)d_in[15]; const float* bv2 = (const float*)d_in[16];
  const float* Ws2 = (const float*)d_in[17]; const float* bs2 = (const float*)d_in[18];
  const float* g2  = (const float*)d_in[19]; const float* be2 = (const float*)d_in[20];
  const int*   ei  = (const int*)d_in[21];

  const int N = in_sizes[0] / IN_DIM;   // 50000
  const int E = in_sizes[21] / 2;       // 800000
  const int* esrc = ei;
  const int* edst = ei + E;

  // ---- workspace carve (256B aligned); deg and st adjacent for single memset
  char* w = (char*)d_ws;
  auto carve = [&](size_t bytes) { char* p = w; w += (bytes + 255) & ~(size_t)255; return p; };
  int* deg   = (int*)carve((size_t)(N + 1) * 4);
  double* st = (double*)carve(64);   // st[0..1]: layer1, st[2..3]: layer2
  u16* x_bf  = (u16*)carve((size_t)N * IN_DIM * 2);          // reused as h1
  u16* Wt1   = (u16*)carve((size_t)4 * HID * IN_DIM * 2);
  u16* Wt2   = (u16*)carve((size_t)4 * OUTD * HID * 2);
  float* bc1 = (float*)carve(4 * HID * 4);
  float* bc2 = (float*)carve(4 * OUTD * 4);
  u16* qkvs1 = (u16*)carve((size_t)N * 4 * HID * 2);         // reused as qkvs2
  u16* a1    = (u16*)carve((size_t)N * HID * 2);
  int* offs  = (int*)carve((size_t)(N + 1) * 4);
  int* cur   = (int*)carve((size_t)(N + 1) * 4);
  int* ssrc  = (int*)carve((size_t)E * 4);
  u16* h1    = x_bf;
  u16* qkvs2 = qkvs1;

  hipMemsetAsync(deg, 0, (size_t)((char*)st - (char*)deg) + 64, stream);

  // ---- K1: mega-prep ----
  int n4 = N * IN_DIM / 4;
  int b_cvt = (n4 + 255) / 256;
  int b_hist = (E + 255) / 256;
  int k1_blocks = b_cvt + b_hist + 6 + 512 + 128;
  k_prep<<<k1_blocks, 256, 0, stream>>>(
      x, x_bf, n4, edst, deg, E,
      bq1, bk1, bv1, bs1, bq2, bk2, bv2, bs2, bc1, bc2,
      Wq1, Wk1, Wv1, Ws1, Wq2, Wk2, Wv2, Ws2, Wt1, Wt2, b_cvt, b_hist);

  // ---- K2: scan ----
  k_scan<<<1, 1024, 0, stream>>>(deg, offs, cur, N, E);

  // ---- K3: gemm1 (xcd-swizzled) + scatter region ----
  int mblk = (N + 127) / 128;                 // 391
  int grp = (mblk + 7) / 8;                   // 49
  int g1_blocks = grp * 8 * 8;                // nbn=8
  k_gemm_sc<<<g1_blocks + b_hist, 256, 0, stream>>>(
      x_bf, Wt1, bc1, qkvs1, N, IN_DIM, 4 * HID, 8, g1_blocks,
      esrc, edst, cur, ssrc, E);

  // ---- K4: conv1 + stats ----
  k_conv<HID, true><<<(N + 3) / 4, 256, 0, stream>>>(qkvs1, offs, ssrc, a1, nullptr, N,
                                                     1.0f / sqrtf((float)HID), st);
  // ---- K5: norm1 + ELU ----
  k_norm_elu_bf16<<<(N * HID / 8 + 255) / 256, 256, 0, stream>>>(
      a1, g1, be1, st, (double)N * HID, h1, N * HID / 8, HID - 1);

  // ---- K6: gemm2 (xcd-swizzled) ----
  int g2_blocks = grp * 8 * 4;                // nbn=4
  k_gemm_sc<<<g2_blocks, 256, 0, stream>>>(
      h1, Wt2, bc2, qkvs2, N, HID, 4 * OUTD, 4, g2_blocks,
      nullptr, nullptr, nullptr, nullptr, 0);

  // ---- K7: conv2 + stats ----
  k_conv<OUTD, false><<<(N + 3) / 4, 256, 0, stream>>>(qkvs2, offs, ssrc, nullptr, (float*)d_out,
                                                       N, 1.0f / sqrtf((float)OUTD), st + 2);
  // ---- K8: norm2 ----
  k_norm_f32<<<(N * OUTD / 4 + 255) / 256, 256, 0, stream>>>(
      (float*)d_out, g2, be2, st + 2, (double)N * OUTD, N * OUTD / 4, OUTD - 1);
}

// Round 7
// 740.371 us; speedup vs baseline: 1.5582x; 1.5582x over previous
//
#include <hip/hip_runtime.h>
#include <stdint.h>
#include <math.h>

#define IN_DIM 512
#define HID    256
#define OUTD   128
#define LN_EPS 1e-5f
#define NSLOT  2048

typedef unsigned short u16;
typedef unsigned int   u32;
typedef short short8 __attribute__((ext_vector_type(8)));
typedef float f32x4  __attribute__((ext_vector_type(4)));

__device__ __forceinline__ float bf2f(u32 h) {
  union { u32 u; float f; } c; c.u = h << 16; return c.f;
}
__device__ __forceinline__ u16 f2bf(float f) {
  union { float f; u32 u; } c; c.f = f;
  u32 u = c.u;
  return (u16)((u + 0x7FFFu + ((u >> 16) & 1u)) >> 16);  // RNE
}

__device__ __forceinline__ void gload_lds16(const void* g, void* l) {
  __builtin_amdgcn_global_load_lds((const __attribute__((address_space(1))) void*)g,
                                   (__attribute__((address_space(3))) void*)l, 16, 0, 0);
}

// ================= K1: mega-prep (block-region dispatch) =====================
// regions: [0,b_cvt) x->bf16 | [.,+b_hist) histogram | [.,+6) bias concat |
//          [.,+512) W1 transpose tiles | [.,+128) W2 transpose tiles
__global__ __launch_bounds__(256) void k_prep(
    const float* __restrict__ x, u16* __restrict__ x_bf, int n4,
    const int* __restrict__ edst, int* __restrict__ deg, int E,
    const float* __restrict__ bq1, const float* __restrict__ bk1,
    const float* __restrict__ bv1, const float* __restrict__ bs1,
    const float* __restrict__ bq2, const float* __restrict__ bk2,
    const float* __restrict__ bv2, const float* __restrict__ bs2,
    float* __restrict__ bc1, float* __restrict__ bc2,
    const float* __restrict__ Wq1, const float* __restrict__ Wk1,
    const float* __restrict__ Wv1, const float* __restrict__ Ws1,
    const float* __restrict__ Wq2, const float* __restrict__ Wk2,
    const float* __restrict__ Wv2, const float* __restrict__ Ws2,
    u16* __restrict__ Wt1, u16* __restrict__ Wt2,
    int b_cvt, int b_hist) {
  __shared__ u16 t[32][33];
  int blk = blockIdx.x;
  int tid = threadIdx.x;
  if (blk < b_cvt) {
    int id = blk * 256 + tid;
    if (id < n4) {
      const float4 v = ((const float4*)x)[id];
      ushort4 o;
      o.x = f2bf(v.x); o.y = f2bf(v.y); o.z = f2bf(v.z); o.w = f2bf(v.w);
      ((ushort4*)x_bf)[id] = o;
    }
    return;
  }
  blk -= b_cvt;
  if (blk < b_hist) {
    int e = blk * 256 + tid;
    if (e < E) atomicAdd(&deg[edst[e]], 1);
    return;
  }
  blk -= b_hist;
  if (blk < 6) {
    int id = blk * 256 + tid;
    if (id < 4 * HID) {
      const float* s = (id < HID) ? bq1 : (id < 2 * HID) ? bk1 : (id < 3 * HID) ? bv1 : bs1;
      bc1[id] = s[id & (HID - 1)];
    } else if (id < 4 * HID + 4 * OUTD) {
      int j = id - 4 * HID;
      const float* s = (j < OUTD) ? bq2 : (j < 2 * OUTD) ? bk2 : (j < 3 * OUTD) ? bv2 : bs2;
      bc2[j] = s[j & (OUTD - 1)];
    }
    return;
  }
  blk -= 6;
  int tx = tid & 31, ty = tid >> 5;
  if (blk < 512) {  // W1: K=512, Nw=256; per-mat 16x8 tiles
    int mat = blk >> 7, r = blk & 127;
    int k0 = (r >> 3) * 32, n0 = (r & 7) * 32;
    const float* src = (mat == 0) ? Wq1 : (mat == 1) ? Wk1 : (mat == 2) ? Wv1 : Ws1;
    u16* dst = Wt1 + (size_t)mat * IN_DIM * HID;
#pragma unroll
    for (int i = 0; i < 32; i += 8)
      t[ty + i][tx] = f2bf(src[(size_t)(k0 + ty + i) * HID + n0 + tx]);
    __syncthreads();
#pragma unroll
    for (int i = 0; i < 32; i += 8)
      dst[(size_t)(n0 + ty + i) * IN_DIM + k0 + tx] = t[tx][ty + i];
    return;
  }
  blk -= 512;
  {  // W2: K=256, Nw=128; per-mat 8x4 tiles
    int mat = blk >> 5, r = blk & 31;
    int k0 = (r >> 2) * 32, n0 = (r & 3) * 32;
    const float* src = (mat == 0) ? Wq2 : (mat == 1) ? Wk2 : (mat == 2) ? Wv2 : Ws2;
    u16* dst = Wt2 + (size_t)mat * HID * OUTD;
#pragma unroll
    for (int i = 0; i < 32; i += 8)
      t[ty + i][tx] = f2bf(src[(size_t)(k0 + ty + i) * OUTD + n0 + tx]);
    __syncthreads();
#pragma unroll
    for (int i = 0; i < 32; i += 8)
      dst[(size_t)(n0 + ty + i) * HID + k0 + tx] = t[tx][ty + i];
  }
}

// ================= K2: single-workgroup exclusive scan =======================
__global__ __launch_bounds__(1024) void k_scan(const int* __restrict__ deg,
                                               int* __restrict__ offsets,
                                               int* __restrict__ cur, int n, int total) {
  __shared__ int sm[1024];
  int t = threadIdx.x;
  int chunk = (n + 1023) / 1024;
  int base = t * chunk;
  int s = 0;
  for (int i = base; i < base + chunk && i < n; ++i) s += deg[i];
  sm[t] = s;
  __syncthreads();
  for (int off = 1; off < 1024; off <<= 1) {
    int v = (t >= off) ? sm[t - off] : 0;
    __syncthreads();
    sm[t] += v;
    __syncthreads();
  }
  int run = sm[t] - s;  // exclusive
  for (int i = base; i < base + chunk && i < n; ++i) {
    offsets[i] = run;
    cur[i] = run;
    run += deg[i];
  }
  if (t == 0) offsets[n] = total;
}

// ================= K3: scatter ==============================================
__global__ void k_scatter(const int* __restrict__ src, const int* __restrict__ dst,
                          int* __restrict__ cursor, int* __restrict__ ssrc, int E) {
  int e = blockIdx.x * blockDim.x + threadIdx.x;
  if (e >= E) return;
  int d = dst[e];
  int pos = atomicAdd(&cursor[d], 1);
  ssrc[pos] = src[e];
}

// ================= K4/K7: bf16 NT GEMM (m97 structure, R5-exact) =============
__global__ __launch_bounds__(256) void k_gemm_bf16_nt(
    const u16* __restrict__ A, const u16* __restrict__ Bt, const float* __restrict__ bias,
    u16* __restrict__ C, int M, int K, int Nt) {
  __shared__ __align__(16) u16 As[128 * 32];
  __shared__ __align__(16) u16 Bs[128 * 32];
  const int tid = threadIdx.x;
  const int bm0 = blockIdx.x * 128;
  const int bn0 = blockIdx.y * 128;
  const int wave = tid >> 6, lane = tid & 63;
  const int q = lane >> 4, r16 = lane & 15;
  const int wm = (wave >> 1) * 64, wn = (wave & 1) * 64;

  f32x4 acc[4][4];
#pragma unroll
  for (int i = 0; i < 4; i++)
#pragma unroll
    for (int j = 0; j < 4; j++) acc[i][j] = (f32x4){0.f, 0.f, 0.f, 0.f};

  const int r0 = tid >> 2;
  const int c0 = (tid & 3) * 8;

  for (int kt = 0; kt < K; kt += 32) {
#pragma unroll
    for (int h = 0; h < 2; ++h) {
      int row = r0 + h * 64;
      gload_lds16(A + (size_t)(bm0 + row) * K + kt + c0, &As[row * 32 + c0]);
      gload_lds16(Bt + (size_t)(bn0 + row) * K + kt + c0, &Bs[row * 32 + c0]);
    }
    __syncthreads();
    short8 af[4], bfr[4];
#pragma unroll
    for (int i = 0; i < 4; i++) af[i] = *(const short8*)(&As[(wm + i * 16 + r16) * 32 + q * 8]);
#pragma unroll
    for (int j = 0; j < 4; j++) bfr[j] = *(const short8*)(&Bs[(wn + j * 16 + r16) * 32 + q * 8]);
#pragma unroll
    for (int i = 0; i < 4; i++)
#pragma unroll
      for (int j = 0; j < 4; j++)
        acc[i][j] = __builtin_amdgcn_mfma_f32_16x16x32_bf16(af[i], bfr[j], acc[i][j], 0, 0, 0);
    __syncthreads();
  }

#pragma unroll
  for (int i = 0; i < 4; i++) {
#pragma unroll
    for (int r = 0; r < 4; r++) {
      int grow = bm0 + wm + i * 16 + q * 4 + r;
      if (grow >= M) continue;
      size_t rbase = (size_t)grow * Nt;
#pragma unroll
      for (int j = 0; j < 4; j++) {
        int gcol = bn0 + wn + j * 16 + r16;
        float v = acc[i][j][r] + bias[gcol];
        C[rbase + gcol] = f2bf(v);
      }
    }
  }
}

// ================= K5/K8: conv (R5-exact body) + spread-slot stats ===========
template <int VPL>
__device__ __forceinline__ void load_bf(const u16* __restrict__ p, int lane, float* f) {
  if constexpr (VPL == 4) {
    uint2 r = *(const uint2*)(p + lane * 4);
    f[0] = bf2f(r.x & 0xffffu); f[1] = bf2f(r.x >> 16);
    f[2] = bf2f(r.y & 0xffffu); f[3] = bf2f(r.y >> 16);
  } else {
    u32 r = *(const u32*)(p + lane * 2);
    f[0] = bf2f(r & 0xffffu); f[1] = bf2f(r >> 16);
  }
}

template <int H, bool OUT_BF16>
__global__ __launch_bounds__(256) void k_conv(
    const u16* __restrict__ qkvs, const int* __restrict__ offsets,
    const int* __restrict__ ssrc, u16* __restrict__ out_bf,
    float* __restrict__ out_f, int n, float scale,
    float* __restrict__ ssum, float* __restrict__ ssq) {
  constexpr int VPL = H / 64;
  int gw = (blockIdx.x * blockDim.x + threadIdx.x) >> 6;
  int wave = threadIdx.x >> 6;
  int lane = threadIdx.x & 63;
  if (gw >= n) return;
  const u16* base = qkvs + (size_t)gw * (4 * H);
  float qf[VPL];
  load_bf<VPL>(base, lane, qf);
  int beg = offsets[gw], end = offsets[gw + 1];
  float m = -INFINITY, l = 0.f;
  float agg[VPL];
#pragma unroll
  for (int w = 0; w < VPL; w++) agg[w] = 0.f;

  int i = beg;
  for (; i + 4 <= end; i += 4) {
    int s0 = ssrc[i], s1 = ssrc[i + 1], s2 = ssrc[i + 2], s3 = ssrc[i + 3];
    const u16* k0p = qkvs + (size_t)s0 * (4 * H) + H;
    const u16* k1p = qkvs + (size_t)s1 * (4 * H) + H;
    const u16* k2p = qkvs + (size_t)s2 * (4 * H) + H;
    const u16* k3p = qkvs + (size_t)s3 * (4 * H) + H;
    float k0[VPL], k1[VPL], k2[VPL], k3[VPL];
    float v0[VPL], v1[VPL], v2[VPL], v3[VPL];
    load_bf<VPL>(k0p, lane, k0);
    load_bf<VPL>(k1p, lane, k1);
    load_bf<VPL>(k2p, lane, k2);
    load_bf<VPL>(k3p, lane, k3);
    load_bf<VPL>(k0p + H, lane, v0);
    load_bf<VPL>(k1p + H, lane, v1);
    load_bf<VPL>(k2p + H, lane, v2);
    load_bf<VPL>(k3p + H, lane, v3);
    float d0 = 0.f, d1 = 0.f, d2 = 0.f, d3 = 0.f;
#pragma unroll
    for (int w = 0; w < VPL; w++) {
      d0 += qf[w] * k0[w]; d1 += qf[w] * k1[w];
      d2 += qf[w] * k2[w]; d3 += qf[w] * k3[w];
    }
#pragma unroll
    for (int off = 32; off > 0; off >>= 1) {
      d0 += __shfl_xor(d0, off, 64);
      d1 += __shfl_xor(d1, off, 64);
      d2 += __shfl_xor(d2, off, 64);
      d3 += __shfl_xor(d3, off, 64);
    }
    d0 *= scale; d1 *= scale; d2 *= scale; d3 *= scale;
    float cm = fmaxf(fmaxf(d0, d1), fmaxf(d2, d3));
    float nm = fmaxf(m, cm);
    float sc = __expf(m - nm);  // m=-inf first round -> 0
    float p0 = __expf(d0 - nm), p1 = __expf(d1 - nm);
    float p2 = __expf(d2 - nm), p3 = __expf(d3 - nm);
    m = nm;
    l = l * sc + (p0 + p1) + (p2 + p3);
#pragma unroll
    for (int w = 0; w < VPL; w++)
      agg[w] = agg[w] * sc + p0 * v0[w] + p1 * v1[w] + p2 * v2[w] + p3 * v3[w];
  }
  for (; i < end; ++i) {
    int s = ssrc[i];
    const u16* kb = qkvs + (size_t)s * (4 * H) + H;
    float kf[VPL], vf[VPL];
    load_bf<VPL>(kb, lane, kf);
    load_bf<VPL>(kb + H, lane, vf);
    float d = 0.f;
#pragma unroll
    for (int w = 0; w < VPL; w++) d += qf[w] * kf[w];
#pragma unroll
    for (int off = 32; off > 0; off >>= 1) d += __shfl_xor(d, off, 64);
    float score = d * scale;
    float nm = fmaxf(m, score);
    float sc = __expf(m - nm);
    float p = __expf(score - nm);
    m = nm;
    l = l * sc + p;
#pragma unroll
    for (int w = 0; w < VPL; w++) agg[w] = agg[w] * sc + p * vf[w];
  }

  float sf[VPL];
  load_bf<VPL>(base + 3 * H, lane, sf);
  float inv = (end > beg) ? 1.f / l : 0.f;
  float r[VPL];
#pragma unroll
  for (int w = 0; w < VPL; w++) {
    r[w] = agg[w] * inv + sf[w];
    if (OUT_BF16) out_bf[(size_t)gw * H + lane * VPL + w] = f2bf(r[w]);
    else out_f[(size_t)gw * H + lane * VPL + w] = r[w];
  }

  // spread-slot stats: per-wave shfl reduce, lane0 atomics to 4096 addresses.
  // No barrier, no LDS (R3/R6 lesson: same-address atomics + end barrier killed conv).
  float s = 0.f, s2 = 0.f;
#pragma unroll
  for (int w = 0; w < VPL; w++) { s += r[w]; s2 += r[w] * r[w]; }
#pragma unroll
  for (int off = 32; off > 0; off >>= 1) {
    s += __shfl_xor(s, off, 64);
    s2 += __shfl_xor(s2, off, 64);
  }
  if (lane == 0) {
    int slot = (blockIdx.x * 4 + wave) & (NSLOT - 1);
    atomicAdd(&ssum[slot], s);
    atomicAdd(&ssq[slot], s2);
  }
}

// ================= K6/K9: layernorm apply (inline slot reduce) ===============
__device__ __forceinline__ void slot_stats(const float* __restrict__ ssum,
                                           const float* __restrict__ ssq,
                                           double cnt, float& mu, float& inv) {
  __shared__ double rs[256], rq[256];
  double ls = 0.0, lq = 0.0;
  for (int i = threadIdx.x; i < NSLOT; i += 256) {
    ls += (double)ssum[i];
    lq += (double)ssq[i];
  }
  rs[threadIdx.x] = ls; rq[threadIdx.x] = lq;
  __syncthreads();
  for (int off = 128; off > 0; off >>= 1) {
    if (threadIdx.x < off) { rs[threadIdx.x] += rs[threadIdx.x + off]; rq[threadIdx.x] += rq[threadIdx.x + off]; }
    __syncthreads();
  }
  double mud = rs[0] / cnt;
  double var = rq[0] / cnt - mud * mud;
  if (var < 0.0) var = 0.0;
  mu = (float)mud;
  inv = (float)(1.0 / (sqrt(var) + (double)LN_EPS));
}

__global__ __launch_bounds__(256) void k_norm_elu_bf16(
    const u16* __restrict__ a, const float* __restrict__ g,
    const float* __restrict__ b, const float* __restrict__ ssum,
    const float* __restrict__ ssq, double cnt,
    u16* __restrict__ out, int n8, int Hmask) {
  float mu, inv;
  slot_stats(ssum, ssq, cnt, mu, inv);
  int id = blockIdx.x * blockDim.x + threadIdx.x;
  if (id >= n8) return;
  int i8 = id * 8;
  int cb = i8 & Hmask;
  uint4 v = *(const uint4*)(a + i8);
  const u32 va[4] = {v.x, v.y, v.z, v.w};
  uint4 o;
  u32* op = (u32*)&o;
#pragma unroll
  for (int w = 0; w < 4; w++) {
    float y0 = (bf2f(va[w] & 0xffffu) - mu) * inv * g[cb + 2 * w] + b[cb + 2 * w];
    float y1 = (bf2f(va[w] >> 16) - mu) * inv * g[cb + 2 * w + 1] + b[cb + 2 * w + 1];
    y0 = (y0 > 0.f) ? y0 : (__expf(y0) - 1.f);
    y1 = (y1 > 0.f) ? y1 : (__expf(y1) - 1.f);
    op[w] = (u32)f2bf(y0) | ((u32)f2bf(y1) << 16);
  }
  *(uint4*)(out + i8) = o;
}

__global__ __launch_bounds__(256) void k_norm_f32(
    float* __restrict__ a, const float* __restrict__ g,
    const float* __restrict__ b, const float* __restrict__ ssum,
    const float* __restrict__ ssq, double cnt, int n4, int Hmask) {
  float mu, inv;
  slot_stats(ssum, ssq, cnt, mu, inv);
  int id = blockIdx.x * blockDim.x + threadIdx.x;
  if (id >= n4) return;
  int i4 = id * 4;
  int cb = i4 & Hmask;
  float4 v = *(const float4*)(a + i4);
  float4 o;
  o.x = (v.x - mu) * inv * g[cb] + b[cb];
  o.y = (v.y - mu) * inv * g[cb + 1] + b[cb + 1];
  o.z = (v.z - mu) * inv * g[cb + 2] + b[cb + 2];
  o.w = (v.w - mu) * inv * g[cb + 3] + b[cb + 3];
  *(float4*)(a + i4) = o;
}

// ================= launch ====================================================
extern "C" void kernel_launch(void* const* d_in, const int* in_sizes, int n_in,
                              void* d_out, int out_size, void* d_ws, size_t ws_size,
                              hipStream_t stream) {
  const float* x   = (const float*)d_in[0];
  const float* Wq1 = (const float*)d_in[1];  const float* bq1 = (const float*)d_in[2];
  const float* Wk1 = (const float*)d_in[3];  const float* bk1 = (const float*)d_in[4];
  const float* Wv1 = (const float*)d_in[5];  const float* bv1 = (const float*)d_in[6];
  const float* Ws1 = (const float*)d_in[7];  const float* bs1 = (const float*)d_in[8];
  const float* g1  = (const float*)d_in[9];  const float* be1 = (const float*)d_in[10];
  const float* Wq2 = (const float*)d_in[11]; const float* bq2 = (const float*)d_in[12];
  const float* Wk2 = (const float*)d_in[13]; const float* bk2 = (const float*)d_in[14];
  const float* Wv2 = (const float*)d_in[15]; const float* bv2 = (const float*)d_in[16];
  const float* Ws2 = (const float*)d_in[17]; const float* bs2 = (const float*)d_in[18];
  const float* g2  = (const float*)d_in[19]; const float* be2 = (const float*)d_in[20];
  const int*   ei  = (const int*)d_in[21];

  const int N = in_sizes[0] / IN_DIM;   // 50000
  const int E = in_sizes[21] / 2;       // 800000
  const int* esrc = ei;
  const int* edst = ei + E;

  // ---- workspace carve (256B aligned); deg + slot arrays adjacent -> 1 memset
  char* w = (char*)d_ws;
  auto carve = [&](size_t bytes) { char* p = w; w += (bytes + 255) & ~(size_t)255; return p; };
  int* deg     = (int*)carve((size_t)(N + 1) * 4);
  float* slots = (float*)carve(4 * NSLOT * 4);  // ssum1|ssq1|ssum2|ssq2
  u16* x_bf  = (u16*)carve((size_t)N * IN_DIM * 2);          // reused as h1
  u16* Wt1   = (u16*)carve((size_t)4 * HID * IN_DIM * 2);
  u16* Wt2   = (u16*)carve((size_t)4 * OUTD * HID * 2);
  float* bc1 = (float*)carve(4 * HID * 4);
  float* bc2 = (float*)carve(4 * OUTD * 4);
  u16* qkvs1 = (u16*)carve((size_t)N * 4 * HID * 2);         // reused as qkvs2
  u16* a1    = (u16*)carve((size_t)N * HID * 2);
  int* offs  = (int*)carve((size_t)(N + 1) * 4);
  int* cur   = (int*)carve((size_t)(N + 1) * 4);
  int* ssrc  = (int*)carve((size_t)E * 4);
  u16* h1    = x_bf;
  u16* qkvs2 = qkvs1;
  float* ssum1 = slots, *ssq1 = slots + NSLOT;
  float* ssum2 = slots + 2 * NSLOT, *ssq2 = slots + 3 * NSLOT;

  hipMemsetAsync(deg, 0, (size_t)((char*)(slots + 4 * NSLOT) - (char*)deg), stream);

  // ---- K1: mega-prep ----
  int n4 = N * IN_DIM / 4;
  int b_cvt = (n4 + 255) / 256;
  int b_hist = (E + 255) / 256;
  int k1_blocks = b_cvt + b_hist + 6 + 512 + 128;
  k_prep<<<k1_blocks, 256, 0, stream>>>(
      x, x_bf, n4, edst, deg, E,
      bq1, bk1, bv1, bs1, bq2, bk2, bv2, bs2, bc1, bc2,
      Wq1, Wk1, Wv1, Ws1, Wq2, Wk2, Wv2, Ws2, Wt1, Wt2, b_cvt, b_hist);

  // ---- K2: scan ----
  k_scan<<<1, 1024, 0, stream>>>(deg, offs, cur, N, E);

  // ---- K3: scatter ----
  k_scatter<<<b_hist, 256, 0, stream>>>(esrc, edst, cur, ssrc, E);

  // ---- K4: gemm1 ----
  dim3 gg1((N + 127) / 128, (4 * HID) / 128);
  k_gemm_bf16_nt<<<gg1, 256, 0, stream>>>(x_bf, Wt1, bc1, qkvs1, N, IN_DIM, 4 * HID);

  // ---- K5: conv1 + spread stats ----
  k_conv<HID, true><<<(N + 3) / 4, 256, 0, stream>>>(qkvs1, offs, ssrc, a1, nullptr, N,
                                                     1.0f / sqrtf((float)HID), ssum1, ssq1);
  // ---- K6: norm1 + ELU ----
  k_norm_elu_bf16<<<N * HID / 8 / 256, 256, 0, stream>>>(
      a1, g1, be1, ssum1, ssq1, (double)N * HID, h1, N * HID / 8, HID - 1);

  // ---- K7: gemm2 ----
  dim3 gg2((N + 127) / 128, (4 * OUTD) / 128);
  k_gemm_bf16_nt<<<gg2, 256, 0, stream>>>(h1, Wt2, bc2, qkvs2, N, HID, 4 * OUTD);

  // ---- K8: conv2 + spread stats ----
  k_conv<OUTD, false><<<(N + 3) / 4, 256, 0, stream>>>(qkvs2, offs, ssrc, nullptr, (float*)d_out,
                                                       N, 1.0f / sqrtf((float)OUTD), ssum2, ssq2);
  // ---- K9: norm2 ----
  k_norm_f32<<<N * OUTD / 4 / 256, 256, 0, stream>>>(
      (float*)d_out, g2, be2, ssum2, ssq2, (double)N * OUTD, N * OUTD / 4, OUTD - 1);
}

// Round 8
// 622.858 us; speedup vs baseline: 1.8522x; 1.1887x over previous
//
#include <hip/hip_runtime.h>
#include <stdint.h>
#include <math.h>

#define IN_DIM 512
#define HID    256
#define OUTD   128
#define LN_EPS 1e-5f
#define NSLOT  2048

typedef unsigned short u16;
typedef unsigned int   u32;
typedef short short8 __attribute__((ext_vector_type(8)));
typedef float f32x4  __attribute__((ext_vector_type(4)));

__device__ __forceinline__ float bf2f(u32 h) {
  union { u32 u; float f; } c; c.u = h << 16; return c.f;
}
__device__ __forceinline__ u16 f2bf(float f) {
  union { float f; u32 u; } c; c.f = f;
  u32 u = c.u;
  return (u16)((u + 0x7FFFu + ((u >> 16) & 1u)) >> 16);  // RNE
}

__device__ __forceinline__ void gload_lds16(const void* g, void* l) {
  __builtin_amdgcn_global_load_lds((const __attribute__((address_space(1))) void*)g,
                                   (__attribute__((address_space(3))) void*)l, 16, 0, 0);
}

// ================= K1: mega-prep (block-region dispatch) =====================
__global__ __launch_bounds__(256) void k_prep(
    const float* __restrict__ x, u16* __restrict__ x_bf, int n4,
    const int* __restrict__ edst, int* __restrict__ deg, int E,
    const float* __restrict__ bq1, const float* __restrict__ bk1,
    const float* __restrict__ bv1, const float* __restrict__ bs1,
    const float* __restrict__ bq2, const float* __restrict__ bk2,
    const float* __restrict__ bv2, const float* __restrict__ bs2,
    float* __restrict__ bc1, float* __restrict__ bc2,
    const float* __restrict__ Wq1, const float* __restrict__ Wk1,
    const float* __restrict__ Wv1, const float* __restrict__ Ws1,
    const float* __restrict__ Wq2, const float* __restrict__ Wk2,
    const float* __restrict__ Wv2, const float* __restrict__ Ws2,
    u16* __restrict__ Wt1, u16* __restrict__ Wt2,
    int b_cvt, int b_hist) {
  __shared__ u16 t[32][33];
  int blk = blockIdx.x;
  int tid = threadIdx.x;
  if (blk < b_cvt) {
    int id = blk * 256 + tid;
    if (id < n4) {
      const float4 v = ((const float4*)x)[id];
      ushort4 o;
      o.x = f2bf(v.x); o.y = f2bf(v.y); o.z = f2bf(v.z); o.w = f2bf(v.w);
      ((ushort4*)x_bf)[id] = o;
    }
    return;
  }
  blk -= b_cvt;
  if (blk < b_hist) {
    int e = blk * 256 + tid;
    if (e < E) atomicAdd(&deg[edst[e]], 1);
    return;
  }
  blk -= b_hist;
  if (blk < 6) {
    int id = blk * 256 + tid;
    if (id < 4 * HID) {
      const float* s = (id < HID) ? bq1 : (id < 2 * HID) ? bk1 : (id < 3 * HID) ? bv1 : bs1;
      bc1[id] = s[id & (HID - 1)];
    } else if (id < 4 * HID + 4 * OUTD) {
      int j = id - 4 * HID;
      const float* s = (j < OUTD) ? bq2 : (j < 2 * OUTD) ? bk2 : (j < 3 * OUTD) ? bv2 : bs2;
      bc2[j] = s[j & (OUTD - 1)];
    }
    return;
  }
  blk -= 6;
  int tx = tid & 31, ty = tid >> 5;
  if (blk < 512) {  // W1: K=512, Nw=256; per-mat 16x8 tiles
    int mat = blk >> 7, r = blk & 127;
    int k0 = (r >> 3) * 32, n0 = (r & 7) * 32;
    const float* src = (mat == 0) ? Wq1 : (mat == 1) ? Wk1 : (mat == 2) ? Wv1 : Ws1;
    u16* dst = Wt1 + (size_t)mat * IN_DIM * HID;
#pragma unroll
    for (int i = 0; i < 32; i += 8)
      t[ty + i][tx] = f2bf(src[(size_t)(k0 + ty + i) * HID + n0 + tx]);
    __syncthreads();
#pragma unroll
    for (int i = 0; i < 32; i += 8)
      dst[(size_t)(n0 + ty + i) * IN_DIM + k0 + tx] = t[tx][ty + i];
    return;
  }
  blk -= 512;
  {  // W2: K=256, Nw=128; per-mat 8x4 tiles
    int mat = blk >> 5, r = blk & 31;
    int k0 = (r >> 2) * 32, n0 = (r & 3) * 32;
    const float* src = (mat == 0) ? Wq2 : (mat == 1) ? Wk2 : (mat == 2) ? Wv2 : Ws2;
    u16* dst = Wt2 + (size_t)mat * HID * OUTD;
#pragma unroll
    for (int i = 0; i < 32; i += 8)
      t[ty + i][tx] = f2bf(src[(size_t)(k0 + ty + i) * OUTD + n0 + tx]);
    __syncthreads();
#pragma unroll
    for (int i = 0; i < 32; i += 8)
      dst[(size_t)(n0 + ty + i) * HID + k0 + tx] = t[tx][ty + i];
  }
}

// ================= K2a/b/c: parallel 3-kernel scan (R5-proven) ===============
__global__ void k_block_sum(const int* __restrict__ deg, int* __restrict__ bsum, int n) {
  __shared__ int sm[256];
  int i = blockIdx.x * 256 + threadIdx.x;
  sm[threadIdx.x] = (i < n) ? deg[i] : 0;
  __syncthreads();
  for (int off = 128; off > 0; off >>= 1) {
    if (threadIdx.x < off) sm[threadIdx.x] += sm[threadIdx.x + off];
    __syncthreads();
  }
  if (threadIdx.x == 0) bsum[blockIdx.x] = sm[0];
}

__global__ void k_scan_bsum(const int* __restrict__ bsum, int* __restrict__ boff, int nb) {
  __shared__ int sm[256];
  int t = threadIdx.x;
  int v = (t < nb) ? bsum[t] : 0;
  sm[t] = v;
  __syncthreads();
  for (int off = 1; off < 256; off <<= 1) {
    int tmp = (t >= off) ? sm[t - off] : 0;
    __syncthreads();
    sm[t] += tmp;
    __syncthreads();
  }
  if (t < nb) boff[t] = sm[t] - v;  // exclusive
}

__global__ void k_scan_final(const int* __restrict__ deg, const int* __restrict__ boff,
                             int* __restrict__ offsets, int* __restrict__ cur,
                             int n, int total) {
  __shared__ int sm[256];
  int t = threadIdx.x;
  int i = blockIdx.x * 256 + t;
  int v = (i < n) ? deg[i] : 0;
  sm[t] = v;
  __syncthreads();
  for (int off = 1; off < 256; off <<= 1) {
    int tmp = (t >= off) ? sm[t - off] : 0;
    __syncthreads();
    sm[t] += tmp;
    __syncthreads();
  }
  if (i < n) {
    int o = boff[blockIdx.x] + sm[t] - v;
    offsets[i] = o;
    cur[i] = o;
  }
  if (i == 0) offsets[n] = total;
}

// ================= K3: scatter ==============================================
__global__ void k_scatter(const int* __restrict__ src, const int* __restrict__ dst,
                          int* __restrict__ cursor, int* __restrict__ ssrc, int E) {
  int e = blockIdx.x * blockDim.x + threadIdx.x;
  if (e >= E) return;
  int d = dst[e];
  int pos = atomicAdd(&cursor[d], 1);
  ssrc[pos] = src[e];
}

// ================= K4/K7: bf16 NT GEMM, 128x256 tile =========================
// 4 waves in 2x2; each wave computes 64x128 via 4x8 mfma 16x16x32.
// acc[4][8]=128 VGPR; ~200 total -> 2 waves/SIMD (launch_bounds(256,2)).
// Staging via global_load_lds w=16 into unpadded stride-32 LDS (m97 pattern).
__global__ __launch_bounds__(256, 2) void k_gemm_bf16_nt(
    const u16* __restrict__ A, const u16* __restrict__ Bt, const float* __restrict__ bias,
    u16* __restrict__ C, int M, int K, int Nt) {
  __shared__ __align__(16) u16 As[128 * 32];   // 8 KB
  __shared__ __align__(16) u16 Bs[256 * 32];   // 16 KB
  const int tid = threadIdx.x;
  const int bm0 = blockIdx.x * 128;
  const int bn0 = blockIdx.y * 256;
  const int wave = tid >> 6, lane = tid & 63;
  const int q = lane >> 4, r16 = lane & 15;
  const int wm = (wave >> 1) * 64;    // 0 / 64
  const int wn = (wave & 1) * 128;    // 0 / 128

  f32x4 acc[4][8];
#pragma unroll
  for (int i = 0; i < 4; i++)
#pragma unroll
    for (int j = 0; j < 8; j++) acc[i][j] = (f32x4){0.f, 0.f, 0.f, 0.f};

  for (int kt = 0; kt < K; kt += 32) {
    // A: 512 chunks of 16B (2/thread); B: 1024 chunks (4/thread).
    // chunk t -> row t>>2, col-chunk (t&3)*8 elems; LDS linear (m104: uniform base + lane*16)
#pragma unroll
    for (int j = 0; j < 2; ++j) {
      int t = j * 256 + tid;
      gload_lds16(A + (size_t)(bm0 + (t >> 2)) * K + kt + (t & 3) * 8, &As[t * 8]);
    }
#pragma unroll
    for (int j = 0; j < 4; ++j) {
      int t = j * 256 + tid;
      gload_lds16(Bt + (size_t)(bn0 + (t >> 2)) * K + kt + (t & 3) * 8, &Bs[t * 8]);
    }
    __syncthreads();
    short8 bfr[8];
#pragma unroll
    for (int j = 0; j < 8; ++j)
      bfr[j] = *(const short8*)(&Bs[(wn + j * 16 + r16) * 32 + q * 8]);
#pragma unroll
    for (int i = 0; i < 4; ++i) {
      short8 af = *(const short8*)(&As[(wm + i * 16 + r16) * 32 + q * 8]);
#pragma unroll
      for (int j = 0; j < 8; ++j)
        acc[i][j] = __builtin_amdgcn_mfma_f32_16x16x32_bf16(af, bfr[j], acc[i][j], 0, 0, 0);
    }
    __syncthreads();
  }

#pragma unroll
  for (int i = 0; i < 4; i++) {
#pragma unroll
    for (int r = 0; r < 4; r++) {
      int grow = bm0 + wm + i * 16 + q * 4 + r;   // C/D: row = quad*4 + reg
      if (grow >= M) continue;
      size_t rbase = (size_t)grow * Nt;
#pragma unroll
      for (int j = 0; j < 8; j++) {
        int gcol = bn0 + wn + j * 16 + r16;       // C/D: col = lane&15
        float v = acc[i][j][r] + bias[gcol];
        C[rbase + gcol] = f2bf(v);
      }
    }
  }
}

// ================= K5/K8: conv (R5 body) + spread-slot stats =================
template <int VPL>
__device__ __forceinline__ void load_bf(const u16* __restrict__ p, int lane, float* f) {
  if constexpr (VPL == 4) {
    uint2 r = *(const uint2*)(p + lane * 4);
    f[0] = bf2f(r.x & 0xffffu); f[1] = bf2f(r.x >> 16);
    f[2] = bf2f(r.y & 0xffffu); f[3] = bf2f(r.y >> 16);
  } else {
    u32 r = *(const u32*)(p + lane * 2);
    f[0] = bf2f(r & 0xffffu); f[1] = bf2f(r >> 16);
  }
}

template <int H, bool OUT_BF16>
__global__ __launch_bounds__(256) void k_conv(
    const u16* __restrict__ qkvs, const int* __restrict__ offsets,
    const int* __restrict__ ssrc, u16* __restrict__ out_bf,
    float* __restrict__ out_f, int n, float scale,
    float* __restrict__ ssum, float* __restrict__ ssq) {
  constexpr int VPL = H / 64;
  int gw = (blockIdx.x * blockDim.x + threadIdx.x) >> 6;
  int wave = threadIdx.x >> 6;
  int lane = threadIdx.x & 63;
  if (gw >= n) return;
  const u16* base = qkvs + (size_t)gw * (4 * H);
  float qf[VPL];
  load_bf<VPL>(base, lane, qf);
  int beg = offsets[gw], end = offsets[gw + 1];
  float m = -INFINITY, l = 0.f;
  float agg[VPL];
#pragma unroll
  for (int w = 0; w < VPL; w++) agg[w] = 0.f;

  int i = beg;
  for (; i + 4 <= end; i += 4) {
    int s0 = ssrc[i], s1 = ssrc[i + 1], s2 = ssrc[i + 2], s3 = ssrc[i + 3];
    const u16* k0p = qkvs + (size_t)s0 * (4 * H) + H;
    const u16* k1p = qkvs + (size_t)s1 * (4 * H) + H;
    const u16* k2p = qkvs + (size_t)s2 * (4 * H) + H;
    const u16* k3p = qkvs + (size_t)s3 * (4 * H) + H;
    float k0[VPL], k1[VPL], k2[VPL], k3[VPL];
    float v0[VPL], v1[VPL], v2[VPL], v3[VPL];
    load_bf<VPL>(k0p, lane, k0);
    load_bf<VPL>(k1p, lane, k1);
    load_bf<VPL>(k2p, lane, k2);
    load_bf<VPL>(k3p, lane, k3);
    load_bf<VPL>(k0p + H, lane, v0);
    load_bf<VPL>(k1p + H, lane, v1);
    load_bf<VPL>(k2p + H, lane, v2);
    load_bf<VPL>(k3p + H, lane, v3);
    float d0 = 0.f, d1 = 0.f, d2 = 0.f, d3 = 0.f;
#pragma unroll
    for (int w = 0; w < VPL; w++) {
      d0 += qf[w] * k0[w]; d1 += qf[w] * k1[w];
      d2 += qf[w] * k2[w]; d3 += qf[w] * k3[w];
    }
#pragma unroll
    for (int off = 32; off > 0; off >>= 1) {
      d0 += __shfl_xor(d0, off, 64);
      d1 += __shfl_xor(d1, off, 64);
      d2 += __shfl_xor(d2, off, 64);
      d3 += __shfl_xor(d3, off, 64);
    }
    d0 *= scale; d1 *= scale; d2 *= scale; d3 *= scale;
    float cm = fmaxf(fmaxf(d0, d1), fmaxf(d2, d3));
    float nm = fmaxf(m, cm);
    float sc = __expf(m - nm);  // m=-inf first round -> 0
    float p0 = __expf(d0 - nm), p1 = __expf(d1 - nm);
    float p2 = __expf(d2 - nm), p3 = __expf(d3 - nm);
    m = nm;
    l = l * sc + (p0 + p1) + (p2 + p3);
#pragma unroll
    for (int w = 0; w < VPL; w++)
      agg[w] = agg[w] * sc + p0 * v0[w] + p1 * v1[w] + p2 * v2[w] + p3 * v3[w];
  }
  for (; i < end; ++i) {
    int s = ssrc[i];
    const u16* kb = qkvs + (size_t)s * (4 * H) + H;
    float kf[VPL], vf[VPL];
    load_bf<VPL>(kb, lane, kf);
    load_bf<VPL>(kb + H, lane, vf);
    float d = 0.f;
#pragma unroll
    for (int w = 0; w < VPL; w++) d += qf[w] * kf[w];
#pragma unroll
    for (int off = 32; off > 0; off >>= 1) d += __shfl_xor(d, off, 64);
    float score = d * scale;
    float nm = fmaxf(m, score);
    float sc = __expf(m - nm);
    float p = __expf(score - nm);
    m = nm;
    l = l * sc + p;
#pragma unroll
    for (int w = 0; w < VPL; w++) agg[w] = agg[w] * sc + p * vf[w];
  }

  float sf[VPL];
  load_bf<VPL>(base + 3 * H, lane, sf);
  float inv = (end > beg) ? 1.f / l : 0.f;
  float r[VPL];
#pragma unroll
  for (int w = 0; w < VPL; w++) {
    r[w] = agg[w] * inv + sf[w];
    if (OUT_BF16) out_bf[(size_t)gw * H + lane * VPL + w] = f2bf(r[w]);
    else out_f[(size_t)gw * H + lane * VPL + w] = r[w];
  }

  // spread-slot stats: no barrier, no LDS, 4096 distinct addresses
  float s = 0.f, s2 = 0.f;
#pragma unroll
  for (int w = 0; w < VPL; w++) { s += r[w]; s2 += r[w] * r[w]; }
#pragma unroll
  for (int off = 32; off > 0; off >>= 1) {
    s += __shfl_xor(s, off, 64);
    s2 += __shfl_xor(s2, off, 64);
  }
  if (lane == 0) {
    int slot = (blockIdx.x * 4 + wave) & (NSLOT - 1);
    atomicAdd(&ssum[slot], s);
    atomicAdd(&ssq[slot], s2);
  }
}

// ================= K6/K9: layernorm apply (inline slot reduce) ===============
__device__ __forceinline__ void slot_stats(const float* __restrict__ ssum,
                                           const float* __restrict__ ssq,
                                           double cnt, float& mu, float& inv) {
  __shared__ double rs[256], rq[256];
  double ls = 0.0, lq = 0.0;
  for (int i = threadIdx.x; i < NSLOT; i += 256) {
    ls += (double)ssum[i];
    lq += (double)ssq[i];
  }
  rs[threadIdx.x] = ls; rq[threadIdx.x] = lq;
  __syncthreads();
  for (int off = 128; off > 0; off >>= 1) {
    if (threadIdx.x < off) { rs[threadIdx.x] += rs[threadIdx.x + off]; rq[threadIdx.x] += rq[threadIdx.x + off]; }
    __syncthreads();
  }
  double mud = rs[0] / cnt;
  double var = rq[0] / cnt - mud * mud;
  if (var < 0.0) var = 0.0;
  mu = (float)mud;
  inv = (float)(1.0 / (sqrt(var) + (double)LN_EPS));
}

__global__ __launch_bounds__(256) void k_norm_elu_bf16(
    const u16* __restrict__ a, const float* __restrict__ g,
    const float* __restrict__ b, const float* __restrict__ ssum,
    const float* __restrict__ ssq, double cnt,
    u16* __restrict__ out, int n8, int Hmask) {
  float mu, inv;
  slot_stats(ssum, ssq, cnt, mu, inv);
  int id = blockIdx.x * blockDim.x + threadIdx.x;
  if (id >= n8) return;
  int i8 = id * 8;
  int cb = i8 & Hmask;
  uint4 v = *(const uint4*)(a + i8);
  const u32 va[4] = {v.x, v.y, v.z, v.w};
  uint4 o;
  u32* op = (u32*)&o;
#pragma unroll
  for (int w = 0; w < 4; w++) {
    float y0 = (bf2f(va[w] & 0xffffu) - mu) * inv * g[cb + 2 * w] + b[cb + 2 * w];
    float y1 = (bf2f(va[w] >> 16) - mu) * inv * g[cb + 2 * w + 1] + b[cb + 2 * w + 1];
    y0 = (y0 > 0.f) ? y0 : (__expf(y0) - 1.f);
    y1 = (y1 > 0.f) ? y1 : (__expf(y1) - 1.f);
    op[w] = (u32)f2bf(y0) | ((u32)f2bf(y1) << 16);
  }
  *(uint4*)(out + i8) = o;
}

__global__ __launch_bounds__(256) void k_norm_f32(
    float* __restrict__ a, const float* __restrict__ g,
    const float* __restrict__ b, const float* __restrict__ ssum,
    const float* __restrict__ ssq, double cnt, int n4, int Hmask) {
  float mu, inv;
  slot_stats(ssum, ssq, cnt, mu, inv);
  int id = blockIdx.x * blockDim.x + threadIdx.x;
  if (id >= n4) return;
  int i4 = id * 4;
  int cb = i4 & Hmask;
  float4 v = *(const float4*)(a + i4);
  float4 o;
  o.x = (v.x - mu) * inv * g[cb] + b[cb];
  o.y = (v.y - mu) * inv * g[cb + 1] + b[cb + 1];
  o.z = (v.z - mu) * inv * g[cb + 2] + b[cb + 2];
  o.w = (v.w - mu) * inv * g[cb + 3] + b[cb + 3];
  *(float4*)(a + i4) = o;
}

// ================= launch ====================================================
extern "C" void kernel_launch(void* const* d_in, const int* in_sizes, int n_in,
                              void* d_out, int out_size, void* d_ws, size_t ws_size,
                              hipStream_t stream) {
  const float* x   = (const float*)d_in[0];
  const float* Wq1 = (const float*)d_in[1];  const float* bq1 = (const float*)d_in[2];
  const float* Wk1 = (const float*)d_in[3];  const float* bk1 = (const float*)d_in[4];
  const float* Wv1 = (const float*)d_in[5];  const float* bv1 = (const float*)d_in[6];
  const float* Ws1 = (const float*)d_in[7];  const float* bs1 = (const float*)d_in[8];
  const float* g1  = (const float*)d_in[9];  const float* be1 = (const float*)d_in[10];
  const float* Wq2 = (const float*)d_in[11]; const float* bq2 = (const float*)d_in[12];
  const float* Wk2 = (const float*)d_in[13]; const float* bk2 = (const float*)d_in[14];
  const float* Wv2 = (const float*)d_in[15]; const float* bv2 = (const float*)d_in[16];
  const float* Ws2 = (const float*)d_in[17]; const float* bs2 = (const float*)d_in[18];
  const float* g2  = (const float*)d_in[19]; const float* be2 = (const float*)d_in[20];
  const int*   ei  = (const int*)d_in[21];

  const int N = in_sizes[0] / IN_DIM;   // 50000
  const int E = in_sizes[21] / 2;       // 800000
  const int* esrc = ei;
  const int* edst = ei + E;

  // ---- workspace carve (256B aligned); deg + slots adjacent -> 1 memset
  char* w = (char*)d_ws;
  auto carve = [&](size_t bytes) { char* p = w; w += (bytes + 255) & ~(size_t)255; return p; };
  int* deg     = (int*)carve((size_t)(N + 1) * 4);
  float* slots = (float*)carve(4 * NSLOT * 4);  // ssum1|ssq1|ssum2|ssq2
  u16* x_bf  = (u16*)carve((size_t)N * IN_DIM * 2);          // reused as h1
  u16* Wt1   = (u16*)carve((size_t)4 * HID * IN_DIM * 2);
  u16* Wt2   = (u16*)carve((size_t)4 * OUTD * HID * 2);
  float* bc1 = (float*)carve(4 * HID * 4);
  float* bc2 = (float*)carve(4 * OUTD * 4);
  u16* qkvs1 = (u16*)carve((size_t)N * 4 * HID * 2);         // reused as qkvs2
  u16* a1    = (u16*)carve((size_t)N * HID * 2);
  int* offs  = (int*)carve((size_t)(N + 1) * 4);
  int* cur   = (int*)carve((size_t)(N + 1) * 4);
  int* ssrc  = (int*)carve((size_t)E * 4);
  int* bsum  = (int*)carve(1024);
  int* boff  = (int*)carve(1024);
  u16* h1    = x_bf;
  u16* qkvs2 = qkvs1;
  float* ssum1 = slots, *ssq1 = slots + NSLOT;
  float* ssum2 = slots + 2 * NSLOT, *ssq2 = slots + 3 * NSLOT;

  hipMemsetAsync(deg, 0, (size_t)((char*)(slots + 4 * NSLOT) - (char*)deg), stream);

  // ---- K1: mega-prep ----
  int n4 = N * IN_DIM / 4;
  int b_cvt = (n4 + 255) / 256;
  int b_hist = (E + 255) / 256;
  int k1_blocks = b_cvt + b_hist + 6 + 512 + 128;
  k_prep<<<k1_blocks, 256, 0, stream>>>(
      x, x_bf, n4, edst, deg, E,
      bq1, bk1, bv1, bs1, bq2, bk2, bv2, bs2, bc1, bc2,
      Wq1, Wk1, Wv1, Ws1, Wq2, Wk2, Wv2, Ws2, Wt1, Wt2, b_cvt, b_hist);

  // ---- K2: parallel scan ----
  int nb = (N + 255) / 256;
  k_block_sum<<<nb, 256, 0, stream>>>(deg, bsum, N);
  k_scan_bsum<<<1, 256, 0, stream>>>(bsum, boff, nb);
  k_scan_final<<<nb, 256, 0, stream>>>(deg, boff, offs, cur, N, E);

  // ---- K3: scatter ----
  k_scatter<<<b_hist, 256, 0, stream>>>(esrc, edst, cur, ssrc, E);

  // ---- K4: gemm1 (128x256 tile) ----
  dim3 gg1((N + 127) / 128, (4 * HID) / 256);
  k_gemm_bf16_nt<<<gg1, 256, 0, stream>>>(x_bf, Wt1, bc1, qkvs1, N, IN_DIM, 4 * HID);

  // ---- K5: conv1 + spread stats ----
  k_conv<HID, true><<<(N + 3) / 4, 256, 0, stream>>>(qkvs1, offs, ssrc, a1, nullptr, N,
                                                     1.0f / sqrtf((float)HID), ssum1, ssq1);
  // ---- K6: norm1 + ELU ----
  k_norm_elu_bf16<<<N * HID / 8 / 256, 256, 0, stream>>>(
      a1, g1, be1, ssum1, ssq1, (double)N * HID, h1, N * HID / 8, HID - 1);

  // ---- K7: gemm2 (128x256 tile) ----
  dim3 gg2((N + 127) / 128, (4 * OUTD) / 256);
  k_gemm_bf16_nt<<<gg2, 256, 0, stream>>>(h1, Wt2, bc2, qkvs2, N, HID, 4 * OUTD);

  // ---- K8: conv2 + spread stats ----
  k_conv<OUTD, false><<<(N + 3) / 4, 256, 0, stream>>>(qkvs2, offs, ssrc, nullptr, (float*)d_out,
                                                       N, 1.0f / sqrtf((float)OUTD), ssum2, ssq2);
  // ---- K9: norm2 ----
  k_norm_f32<<<N * OUTD / 4 / 256, 256, 0, stream>>>(
      (float*)d_out, g2, be2, ssum2, ssq2, (double)N * OUTD, N * OUTD / 4, OUTD - 1);
}